// Round 6
// baseline (902.921 us; speedup 1.0000x reference)
//
#include <hip/hip_runtime.h>

typedef unsigned short u16;
typedef __bf16 bf16x8 __attribute__((ext_vector_type(8)));
typedef float f32x4 __attribute__((ext_vector_type(4)));

static __device__ __forceinline__ u16 f2bf(float f) {
  unsigned u = __builtin_bit_cast(unsigned, f);
  u = u + 0x7FFFu + ((u >> 16) & 1u);   // RNE
  return (u16)(u >> 16);
}
static __device__ __forceinline__ float bf2f(u16 h) {
  return __builtin_bit_cast(float, (unsigned)h << 16);
}

#define GLOAD_LDS16(g, l) __builtin_amdgcn_global_load_lds(              \
    (const __attribute__((address_space(1))) void*)(g),                  \
    (__attribute__((address_space(3))) void*)(l), 16, 0, 0)
#define BAR() asm volatile("s_barrier" ::: "memory")
#define VMCNT(n) asm volatile("s_waitcnt vmcnt(" #n ")" ::: "memory")
#define LGKM0() do { asm volatile("s_waitcnt lgkmcnt(0)" ::: "memory");   \
                     __builtin_amdgcn_sched_barrier(0); } while (0)

// ---------------- elementwise f32 -> bf16 (4 elems/thread) ----------------
__global__ __launch_bounds__(256) void cvt_f32_bf16(const float* __restrict__ in,
                                                    u16* __restrict__ out, long n4) {
  long i = (long)blockIdx.x * 256 + threadIdx.x;
  if (i >= n4) return;
  float4 v = reinterpret_cast<const float4*>(in)[i];
  ushort4 o;
  o.x = f2bf(v.x); o.y = f2bf(v.y); o.z = f2bf(v.z); o.w = f2bf(v.w);
  reinterpret_cast<ushort4*>(out)[i] = o;
}

// ------------- transpose + convert: W[K][N] f32 -> Wt[N][K] bf16 ----------
__global__ __launch_bounds__(256) void transpose_cvt(const float* __restrict__ W,
                                                     u16* __restrict__ Wt,
                                                     int K, int N) {
  __shared__ float tile[32][33];
  const int tx = threadIdx.x & 31, ty = threadIdx.x >> 5;  // ty: 0..7
  const int n0 = blockIdx.x * 32, k0 = blockIdx.y * 32;
#pragma unroll
  for (int i = 0; i < 4; ++i)
    tile[ty + i * 8][tx] = W[(long)(k0 + ty + i * 8) * N + n0 + tx];
  __syncthreads();
#pragma unroll
  for (int i = 0; i < 4; ++i) {
    int r = ty + i * 8;
    Wt[(long)(n0 + r) * K + k0 + tx] = f2bf(tile[tx][r]);
  }
}

// -------- y [16][77][768] f32 -> yp [16][80][768] bf16, pad rows = 0 -------
__global__ __launch_bounds__(256) void cvt_y_pad(const float* __restrict__ y,
                                                 u16* __restrict__ yp) {
  int idx = blockIdx.x * 256 + threadIdx.x;
  int e = idx * 4;  // element index into [16][80][768]
  int c = e % 768;
  int rb = e / 768;
  int r = rb % 80, b = rb / 80;
  ushort4 o;
  if (r < 77) {
    float4 v = *reinterpret_cast<const float4*>(y + ((long)(b * 77 + r) * 768 + c));
    o.x = f2bf(v.x); o.y = f2bf(v.y); o.z = f2bf(v.z); o.w = f2bf(v.w);
  } else {
    o.x = 0; o.y = 0; o.z = 0; o.w = 0;
  }
  *reinterpret_cast<ushort4*>(yp + e) = o;
}

// ---------------- bias concat: bkv = [bk | bv], 2048 f32 ------------------
__global__ __launch_bounds__(256) void concat_bias(const float* __restrict__ a,
                                                   const float* __restrict__ b,
                                                   float* __restrict__ o) {
  int i = blockIdx.x * 256 + threadIdx.x;
  o[i] = (i < 1024) ? a[i] : b[i - 1024];
}

// -- KV [16][80][2048] bf16 (V at col 1024) -> Vt [16][1024][96] (pad 0) ----
__global__ __launch_bounds__(256) void transpose_v(const u16* __restrict__ KV,
                                                   u16* __restrict__ Vt) {
  __shared__ u16 tile[32][34];
  const int tx = threadIdx.x & 31, ty = threadIdx.x >> 5;  // ty: 0..7
  const int b = blockIdx.z;
  const int k0 = blockIdx.y * 32;   // 0,32,64
  const int e0 = blockIdx.x * 32;
  const u16* src = KV + (long)b * 80 * 2048 + 1024;
#pragma unroll
  for (int i = 0; i < 4; ++i) {
    int k = k0 + ty + i * 8;
    tile[ty + i * 8][tx] = (k < 80) ? src[(long)k * 2048 + e0 + tx] : (u16)0;
  }
  __syncthreads();
  u16* dst = Vt + (long)b * 1024 * 96;
#pragma unroll
  for (int i = 0; i < 4; ++i) {
    int e = e0 + ty + i * 8;
    dst[(long)e * 96 + k0 + tx] = tile[tx][ty + i * 8];
  }
}

// ============ 256x256 m201-style 8-phase bf16 GEMM, C = A @ Bt^T + bias ====
template <bool OUT_BF16>
__global__ __launch_bounds__(512, 2) void gemm8(const u16* __restrict__ A,
                                                const u16* __restrict__ Bt,
                                                const float* __restrict__ bias,
                                                void* __restrict__ Cv,
                                                int M, int N, int K) {
  extern __shared__ __align__(16) u16 lds[];
  const int tid = threadIdx.x;
  const int lane = tid & 63, wid = tid >> 6;
  const int lr = lane & 15, lk = lane >> 4;
  const int wr = wid >> 2, wc = wid & 3;

  // T1: chunked XCD swizzle (bijective when grid % 8 == 0)
  int flat = blockIdx.x;
  int nb = gridDim.x;
  int widx = flat;
  if ((nb & 7) == 0) {
    int per = nb >> 3;
    widx = (flat & 7) * per + (flat >> 3);
  }
  const int nbx = N >> 8;
  const long m0 = (long)(widx / nbx) * 256;
  const long n0 = (long)(widx % nbx) * 256;
  const int nt = K >> 6;

  f32x4 acc[8][4] = {};

  const long abase = m0 * (long)K;
  const long bbase = n0 * (long)K;
  const int srl = tid >> 3;
  const int scl = tid & 7;

#define STAGE_HALF(SRC, sbase, t_, half_, ldsbase)                           \
  do {                                                                       \
    long k0_ = (long)(t_) * 64;                                              \
    _Pragma("unroll")                                                        \
    for (int j_ = 0; j_ < 2; ++j_) {                                         \
      int row_ = (half_) * 128 + j_ * 64 + srl;                              \
      int cg_ = scl ^ (row_ & 7);                                            \
      GLOAD_LDS16(SRC + (sbase) + (long)row_ * K + k0_ + cg_ * 8,            \
                  lds + (ldsbase) + row_ * 64 + scl * 8);                    \
    }                                                                        \
  } while (0)

#define LDB_ALL(p)                                                           \
  _Pragma("unroll")                                                          \
  for (int n_ = 0; n_ < 4; ++n_)                                             \
    _Pragma("unroll")                                                        \
    for (int kk_ = 0; kk_ < 2; ++kk_) {                                      \
      int row_ = wc * 64 + n_ * 16 + lr;                                     \
      int ch_ = (kk_ * 4 + lk) ^ (lr & 7);                                   \
      bq[n_][kk_] = *reinterpret_cast<const bf16x8*>(                        \
          lds + 32768 + (p) * 16384 + row_ * 64 + ch_ * 8);                  \
    }

#define LDA_Q(p, q)                                                          \
  _Pragma("unroll")                                                          \
  for (int i_ = 0; i_ < 2; ++i_)                                             \
    _Pragma("unroll")                                                        \
    for (int kk_ = 0; kk_ < 2; ++kk_) {                                      \
      int row_ = wr * 128 + ((q) * 2 + i_) * 16 + lr;                        \
      int ch_ = (kk_ * 4 + lk) ^ (lr & 7);                                   \
      af[i_][kk_] = *reinterpret_cast<const bf16x8*>(                        \
          lds + (p) * 16384 + row_ * 64 + ch_ * 8);                          \
    }

// kk_ outermost: 8 independent MFMAs between dependent accumulator reuses
#define MFMA_Q(q)                                                            \
  __builtin_amdgcn_s_setprio(1);                                             \
  _Pragma("unroll")                                                          \
  for (int kk_ = 0; kk_ < 2; ++kk_)                                          \
    _Pragma("unroll")                                                        \
    for (int i_ = 0; i_ < 2; ++i_)                                           \
      _Pragma("unroll")                                                      \
      for (int n_ = 0; n_ < 4; ++n_)                                         \
        acc[(q) * 2 + i_][n_] = __builtin_amdgcn_mfma_f32_16x16x32_bf16(     \
            af[i_][kk_], bq[n_][kk_], acc[(q) * 2 + i_][n_], 0, 0, 0);       \
  __builtin_amdgcn_s_setprio(0);

  STAGE_HALF(A, abase, 0, 0, 0);
  STAGE_HALF(A, abase, 0, 1, 0);
  STAGE_HALF(Bt, bbase, 0, 0, 32768);
  STAGE_HALF(Bt, bbase, 0, 1, 32768);
  STAGE_HALF(Bt, bbase, 1, 0, 49152);
  STAGE_HALF(Bt, bbase, 1, 1, 49152);
  VMCNT(4);
  BAR();

  const int niter = nt >> 1;
  for (int tp = 0; tp < niter; ++tp) {
    const int T = tp << 1;
    const bool more = (T + 2 < nt);
    bf16x8 af[2][2], bq[4][2];

    // ---- tile T (parity 0) ----
    LDB_ALL(0); LDA_Q(0, 0);
    STAGE_HALF(A, abase, T + 1, 0, 16384);
    BAR(); LGKM0(); MFMA_Q(0); BAR();
    LDA_Q(0, 1);
    STAGE_HALF(A, abase, T + 1, 1, 16384);
    BAR(); LGKM0(); MFMA_Q(1); BAR();
    LDA_Q(0, 2);
    if (more) STAGE_HALF(Bt, bbase, T + 2, 0, 32768);
    BAR(); LGKM0(); MFMA_Q(2); BAR();
    LDA_Q(0, 3);
    if (more) { STAGE_HALF(Bt, bbase, T + 2, 1, 32768); VMCNT(4); }
    else VMCNT(0);
    BAR(); LGKM0(); MFMA_Q(3); BAR();

    // ---- tile T+1 (parity 1) ----
    LDB_ALL(1); LDA_Q(1, 0);
    if (more) STAGE_HALF(A, abase, T + 2, 0, 0);
    BAR(); LGKM0(); MFMA_Q(0); BAR();
    LDA_Q(1, 1);
    if (more) STAGE_HALF(A, abase, T + 2, 1, 0);
    BAR(); LGKM0(); MFMA_Q(1); BAR();
    LDA_Q(1, 2);
    if (more) STAGE_HALF(Bt, bbase, T + 3, 0, 49152);
    BAR(); LGKM0(); MFMA_Q(2); BAR();
    LDA_Q(1, 3);
    if (more) { STAGE_HALF(Bt, bbase, T + 3, 1, 49152); VMCNT(4); }
    BAR(); LGKM0(); MFMA_Q(3); BAR();
  }

  const long mrow = m0 + wr * 128;
  const long ncol = n0 + wc * 64;

  if (OUT_BF16) {
#pragma unroll
    for (int n = 0; n < 4; ++n) {
      long col = ncol + n * 16 + lr;
      float bb = bias[col];
#pragma unroll
      for (int m = 0; m < 8; ++m)
#pragma unroll
        for (int j = 0; j < 4; ++j) {
          long row = mrow + m * 16 + lk * 4 + j;
          unsigned h = f2bf(acc[m][n][j] + bb);
          unsigned ph = h | (((unsigned)__shfl_xor((int)h, 1, 64)) << 16);
          unsigned p2 = (unsigned)__shfl_xor((int)ph, 2, 64);
          if ((lane & 3) == 0) {
            uint2 o; o.x = ph; o.y = p2;
            *reinterpret_cast<uint2*>((u16*)Cv + row * N + col) = o;
          }
        }
    }
  } else {
    // f32 epilogue: per-wave LDS transpose (stride 68 = 2-way = free) ->
    // coalesced f32x4 nontemporal stores (16 rows x 64 cols per m-step).
    __syncthreads();                         // LDS tiles no longer needed
    float* ep = reinterpret_cast<float*>(lds) + wid * (16 * 68);
    float bb[4];
#pragma unroll
    for (int n = 0; n < 4; ++n) bb[n] = bias[ncol + n * 16 + lr];
    const int er = lane >> 2, ec = (lane & 3) * 16;
#pragma unroll
    for (int m = 0; m < 8; ++m) {
#pragma unroll
      for (int n = 0; n < 4; ++n)
#pragma unroll
        for (int j = 0; j < 4; ++j)
          ep[(lk * 4 + j) * 68 + n * 16 + lr] = acc[m][n][j] + bb[n];
      asm volatile("s_waitcnt lgkmcnt(0)" ::: "memory");
      float* dst = (float*)Cv + (mrow + m * 16 + er) * N + ncol + ec;
#pragma unroll
      for (int q = 0; q < 4; ++q) {
        f32x4 v = *reinterpret_cast<const f32x4*>(ep + er * 68 + ec + q * 4);
        __builtin_nontemporal_store(v, reinterpret_cast<f32x4*>(dst + q * 4));
      }
      asm volatile("s_waitcnt lgkmcnt(0)" ::: "memory");
    }
  }
#undef STAGE_HALF
#undef LDB_ALL
#undef LDA_Q
#undef MFMA_Q
}

// ---------------- fused attention: 16 q-rows per block, in-place on Q ------
// Q [16*4096][1024] bf16 (overwritten), KV [16][80][2048] bf16 (K = cols
// 0..1023; rows 77..79 masked), Vt [16][1024][96] bf16 (k-pad zeroed).
__global__ __launch_bounds__(256) void attn_fused(u16* __restrict__ Q,
                                                  const u16* __restrict__ KV,
                                                  const u16* __restrict__ Vt) {
  const int blk = blockIdx.x;
  const int b = blk >> 8;               // 256 blocks per batch (4096/16)
  const int q0 = (blk & 255) << 4;
  const long qoff = ((long)b * 4096 + q0) * 1024;
  const int tid = threadIdx.x;
  const int lane = tid & 63, wave = tid >> 6;
  const int lr = lane & 15, lk = lane >> 4;

  __shared__ float S4[4][16][80];
  __shared__ __align__(16) u16 P_lds[16][104];  // bf16 P, stride 104 breaks banks

  // Phase 1: scores via MFMA; wave w covers k-dim slice w*256 .. +255
  f32x4 acc[5] = {};
  const u16* qb = Q + qoff;
  const u16* kb = KV + (long)b * 80 * 2048;
#pragma unroll
  for (int t = 0; t < 8; ++t) {
    int kk = wave * 8 + t;
    bf16x8 qa = *reinterpret_cast<const bf16x8*>(qb + lr * 1024 + kk * 32 + lk * 8);
#pragma unroll
    for (int n = 0; n < 5; ++n) {
      bf16x8 kf = *reinterpret_cast<const bf16x8*>(kb + (long)(n * 16 + lr) * 2048 + kk * 32 + lk * 8);
      acc[n] = __builtin_amdgcn_mfma_f32_16x16x32_bf16(qa, kf, acc[n], 0, 0, 0);
    }
  }
#pragma unroll
  for (int n = 0; n < 5; ++n)
#pragma unroll
    for (int j = 0; j < 4; ++j)
      S4[wave][lk * 4 + j][n * 16 + lr] = acc[n][j];
  __syncthreads();

  // Phase 2: cross-wave reduce + softmax -> P_lds (bf16, cols 80..95 zeroed)
  {
    const int r = tid >> 4, ci = tid & 15;
    const float scale = 0.088388347648318447f;  // 1/sqrt(128)
    float v[5];
    float mx = -3e38f;
#pragma unroll
    for (int i = 0; i < 5; ++i) {
      int c = ci + 16 * i;
      float s = (S4[0][r][c] + S4[1][r][c]) + (S4[2][r][c] + S4[3][r][c]);
      s *= scale;
      if (c >= 77) s = -3e38f;
      v[i] = s;
      mx = fmaxf(mx, s);
    }
#pragma unroll
    for (int off = 1; off < 16; off <<= 1) mx = fmaxf(mx, __shfl_xor(mx, off, 64));
    float sum = 0.f, e[5];
#pragma unroll
    for (int i = 0; i < 5; ++i) { e[i] = __expf(v[i] - mx); sum += e[i]; }
#pragma unroll
    for (int off = 1; off < 16; off <<= 1) sum += __shfl_xor(sum, off, 64);
    float inv = 1.f / sum;
#pragma unroll
    for (int i = 0; i < 5; ++i) P_lds[r][ci + 16 * i] = f2bf(e[i] * inv);
    P_lds[r][80 + ci] = 0;
  }
  __syncthreads();

  // Phase 3: PV via MFMA. A = P (rows = q), B = Vt rows (cols = e), K = 96.
  bf16x8 pa[3];
#pragma unroll
  for (int kk = 0; kk < 3; ++kk)
    pa[kk] = *reinterpret_cast<const bf16x8*>(&P_lds[lr][kk * 32 + lk * 8]);
  const u16* vt = Vt + (long)b * 1024 * 96;
  u16* ob = Q + qoff;
#pragma unroll
  for (int n = 0; n < 16; ++n) {
    int col = wave * 256 + n * 16 + lr;
    f32x4 o = {};
#pragma unroll
    for (int kk = 0; kk < 3; ++kk) {
      bf16x8 vq = *reinterpret_cast<const bf16x8*>(vt + (long)col * 96 + kk * 32 + lk * 8);
      o = __builtin_amdgcn_mfma_f32_16x16x32_bf16(pa[kk], vq, o, 0, 0, 0);
    }
#pragma unroll
    for (int j = 0; j < 4; ++j) {
      unsigned h = f2bf(o[j]);
      unsigned ph = h | (((unsigned)__shfl_xor((int)h, 1, 64)) << 16);
      unsigned p2 = (unsigned)__shfl_xor((int)ph, 2, 64);
      if ((lane & 3) == 0) {
        uint2 st; st.x = ph; st.y = p2;
        *reinterpret_cast<uint2*>(ob + (long)(lk * 4 + j) * 1024 + col) = st;
      }
    }
  }
}

extern "C" void kernel_launch(void* const* d_in, const int* in_sizes, int n_in,
                              void* d_out, int out_size, void* d_ws, size_t ws_size,
                              hipStream_t stream) {
  const float* x  = (const float*)d_in[0];
  const float* y  = (const float*)d_in[1];
  const float* Wq = (const float*)d_in[2];
  const float* bq = (const float*)d_in[3];
  const float* Wk = (const float*)d_in[4];
  const float* bk = (const float*)d_in[5];
  const float* Wv = (const float*)d_in[6];
  const float* bv = (const float*)d_in[7];
  const float* Wo = (const float*)d_in[8];
  const float* bo = (const float*)d_in[9];

  const int B = 16, Lq = 4096, D = 1024, Dc = 768, Lp = 80;
  const long Mq = (long)B * Lq;  // 65536

  char* p = (char*)d_ws;
  u16* Qb   = (u16*)p; p += (size_t)Mq * D * 2;       // Q, then attn out (in-place)
  u16* Wqt  = (u16*)p; p += (size_t)D * D * 2;
  u16* Wkvt = (u16*)p; p += (size_t)2 * D * Dc * 2;   // [2048][768]: Wk^T | Wv^T
  u16* Wot  = (u16*)p; p += (size_t)D * D * 2;
  u16* yp   = (u16*)p; p += (size_t)B * Lp * Dc * 2;  // [16][80][768], pad zeroed
  u16* KV   = (u16*)p; p += (size_t)B * Lp * 2 * D * 2; // [16][80][2048]
  u16* Vt   = (u16*)p; p += (size_t)B * D * 96 * 2;   // [16][1024][96]
  float* bkv = (float*)p; p += (size_t)2 * D * 4;     // [2048]
  u16* xb   = (u16*)d_out;  // scratch: x as bf16 lives in d_out until final GEMM

  (void)hipFuncSetAttribute(reinterpret_cast<const void*>(&gemm8<true>),
                            hipFuncAttributeMaxDynamicSharedMemorySize, 131072);
  (void)hipFuncSetAttribute(reinterpret_cast<const void*>(&gemm8<false>),
                            hipFuncAttributeMaxDynamicSharedMemorySize, 131072);

  // conversions
  cvt_f32_bf16<<<(int)(Mq * D / 1024), 256, 0, stream>>>(x, xb, Mq * D / 4);
  transpose_cvt<<<dim3(D / 32, D / 32), 256, 0, stream>>>(Wq, Wqt, D, D);
  transpose_cvt<<<dim3(D / 32, Dc / 32), 256, 0, stream>>>(Wk, Wkvt, Dc, D);
  transpose_cvt<<<dim3(D / 32, Dc / 32), 256, 0, stream>>>(Wv, Wkvt + (size_t)D * Dc, Dc, D);
  transpose_cvt<<<dim3(D / 32, D / 32), 256, 0, stream>>>(Wo, Wot, D, D);
  cvt_y_pad<<<(B * Lp * Dc / 4) / 256, 256, 0, stream>>>(y, yp);
  concat_bias<<<8, 256, 0, stream>>>(bk, bv, bkv);

  // fused K|V projection: [1280][768] @ [768][2048] -> [1280][2048]
  gemm8<true><<<(1280 / 256) * (2 * D / 256), 512, 131072, stream>>>(
      yp, Wkvt, bkv, KV, B * Lp, 2 * D, Dc);

  // V transpose for MFMA PV: KV cols 1024.. -> [16][1024][96]
  transpose_v<<<dim3(D / 32, 3, B), 256, 0, stream>>>(KV, Vt);

  // Q projection: [65536][1024] @ [1024][1024] -> [65536][1024] bf16
  gemm8<true><<<(int)(Mq / 256) * (D / 256), 512, 131072, stream>>>(xb, Wqt, bq, Qb, (int)Mq, D, D);

  // fused attention, writes back into Qb
  attn_fused<<<(int)(Mq / 16), 256, 0, stream>>>(Qb, KV, Vt);

  // output projection: [65536][1024] @ [1024][1024] -> d_out f32
  gemm8<false><<<(int)(Mq / 256) * (D / 256), 512, 131072, stream>>>(Qb, Wot, bo, d_out, (int)Mq, D, D);
}

// Round 7
// 640.202 us; speedup vs baseline: 1.4104x; 1.4104x over previous
//
#include <hip/hip_runtime.h>

typedef unsigned short u16;
typedef __bf16 bf16x8 __attribute__((ext_vector_type(8)));
typedef float f32x4 __attribute__((ext_vector_type(4)));

static __device__ __forceinline__ u16 f2bf(float f) {
  unsigned u = __builtin_bit_cast(unsigned, f);
  u = u + 0x7FFFu + ((u >> 16) & 1u);   // RNE
  return (u16)(u >> 16);
}
static __device__ __forceinline__ float bf2f(u16 h) {
  return __builtin_bit_cast(float, (unsigned)h << 16);
}

#define GLOAD_LDS16(g, l) __builtin_amdgcn_global_load_lds(              \
    (const __attribute__((address_space(1))) void*)(g),                  \
    (__attribute__((address_space(3))) void*)(l), 16, 0, 0)
#define BAR() asm volatile("s_barrier" ::: "memory")
#define VMCNT(n) asm volatile("s_waitcnt vmcnt(" #n ")" ::: "memory")
#define LGKM0() do { asm volatile("s_waitcnt lgkmcnt(0)" ::: "memory");   \
                     __builtin_amdgcn_sched_barrier(0); } while (0)

// ---------------- elementwise f32 -> bf16 (4 elems/thread) ----------------
__global__ __launch_bounds__(256) void cvt_f32_bf16(const float* __restrict__ in,
                                                    u16* __restrict__ out, long n4) {
  long i = (long)blockIdx.x * 256 + threadIdx.x;
  if (i >= n4) return;
  float4 v = reinterpret_cast<const float4*>(in)[i];
  ushort4 o;
  o.x = f2bf(v.x); o.y = f2bf(v.y); o.z = f2bf(v.z); o.w = f2bf(v.w);
  reinterpret_cast<ushort4*>(out)[i] = o;
}

// ------------- transpose + convert: W[K][N] f32 -> Wt[N][K] bf16 ----------
__global__ __launch_bounds__(256) void transpose_cvt(const float* __restrict__ W,
                                                     u16* __restrict__ Wt,
                                                     int K, int N) {
  __shared__ float tile[32][33];
  const int tx = threadIdx.x & 31, ty = threadIdx.x >> 5;  // ty: 0..7
  const int n0 = blockIdx.x * 32, k0 = blockIdx.y * 32;
#pragma unroll
  for (int i = 0; i < 4; ++i)
    tile[ty + i * 8][tx] = W[(long)(k0 + ty + i * 8) * N + n0 + tx];
  __syncthreads();
#pragma unroll
  for (int i = 0; i < 4; ++i) {
    int r = ty + i * 8;
    Wt[(long)(n0 + r) * K + k0 + tx] = f2bf(tile[tx][r]);
  }
}

// -------- y [16][77][768] f32 -> yp [16][80][768] bf16, pad rows = 0 -------
__global__ __launch_bounds__(256) void cvt_y_pad(const float* __restrict__ y,
                                                 u16* __restrict__ yp) {
  int idx = blockIdx.x * 256 + threadIdx.x;
  int e = idx * 4;  // element index into [16][80][768]
  int c = e % 768;
  int rb = e / 768;
  int r = rb % 80, b = rb / 80;
  ushort4 o;
  if (r < 77) {
    float4 v = *reinterpret_cast<const float4*>(y + ((long)(b * 77 + r) * 768 + c));
    o.x = f2bf(v.x); o.y = f2bf(v.y); o.z = f2bf(v.z); o.w = f2bf(v.w);
  } else {
    o.x = 0; o.y = 0; o.z = 0; o.w = 0;
  }
  *reinterpret_cast<ushort4*>(yp + e) = o;
}

// ---------------- bias concat: bkv = [bk | bv], 2048 f32 ------------------
__global__ __launch_bounds__(256) void concat_bias(const float* __restrict__ a,
                                                   const float* __restrict__ b,
                                                   float* __restrict__ o) {
  int i = blockIdx.x * 256 + threadIdx.x;
  o[i] = (i < 1024) ? a[i] : b[i - 1024];
}

// -- KV [16][80][2048] bf16 (V at col 1024) -> Vt [16][1024][96] (pad 0) ----
__global__ __launch_bounds__(256) void transpose_v(const u16* __restrict__ KV,
                                                   u16* __restrict__ Vt) {
  __shared__ u16 tile[32][34];
  const int tx = threadIdx.x & 31, ty = threadIdx.x >> 5;  // ty: 0..7
  const int b = blockIdx.z;
  const int k0 = blockIdx.y * 32;   // 0,32,64
  const int e0 = blockIdx.x * 32;
  const u16* src = KV + (long)b * 80 * 2048 + 1024;
#pragma unroll
  for (int i = 0; i < 4; ++i) {
    int k = k0 + ty + i * 8;
    tile[ty + i * 8][tx] = (k < 80) ? src[(long)k * 2048 + e0 + tx] : (u16)0;
  }
  __syncthreads();
  u16* dst = Vt + (long)b * 1024 * 96;
#pragma unroll
  for (int i = 0; i < 4; ++i) {
    int e = e0 + ty + i * 8;
    dst[(long)e * 96 + k0 + tx] = tile[tx][ty + i * 8];
  }
}

// ============ 256x256 m201-style 8-phase bf16 GEMM, C = A @ Bt^T + bias ====
template <bool OUT_BF16>
__global__ __launch_bounds__(512, 2) void gemm8(const u16* __restrict__ A,
                                                const u16* __restrict__ Bt,
                                                const float* __restrict__ bias,
                                                void* __restrict__ Cv,
                                                int M, int N, int K) {
  extern __shared__ __align__(16) u16 lds[];
  const int tid = threadIdx.x;
  const int lane = tid & 63, wid = tid >> 6;
  const int lr = lane & 15, lk = lane >> 4;
  const int wr = wid >> 2, wc = wid & 3;

  // T1: chunked XCD swizzle (bijective when grid % 8 == 0)
  int flat = blockIdx.x;
  int nb = gridDim.x;
  int widx = flat;
  if ((nb & 7) == 0) {
    int per = nb >> 3;
    widx = (flat & 7) * per + (flat >> 3);
  }
  const int nbx = N >> 8;
  const long m0 = (long)(widx / nbx) * 256;
  const long n0 = (long)(widx % nbx) * 256;
  const int nt = K >> 6;

  f32x4 acc[8][4] = {};

  const long abase = m0 * (long)K;
  const long bbase = n0 * (long)K;
  const int srl = tid >> 3;
  const int scl = tid & 7;

#define STAGE_HALF(SRC, sbase, t_, half_, ldsbase)                           \
  do {                                                                       \
    long k0_ = (long)(t_) * 64;                                              \
    _Pragma("unroll")                                                        \
    for (int j_ = 0; j_ < 2; ++j_) {                                         \
      int row_ = (half_) * 128 + j_ * 64 + srl;                              \
      int cg_ = scl ^ (row_ & 7);                                            \
      GLOAD_LDS16(SRC + (sbase) + (long)row_ * K + k0_ + cg_ * 8,            \
                  lds + (ldsbase) + row_ * 64 + scl * 8);                    \
    }                                                                        \
  } while (0)

#define LDB_ALL(p)                                                           \
  _Pragma("unroll")                                                          \
  for (int n_ = 0; n_ < 4; ++n_)                                             \
    _Pragma("unroll")                                                        \
    for (int kk_ = 0; kk_ < 2; ++kk_) {                                      \
      int row_ = wc * 64 + n_ * 16 + lr;                                     \
      int ch_ = (kk_ * 4 + lk) ^ (lr & 7);                                   \
      bq[n_][kk_] = *reinterpret_cast<const bf16x8*>(                        \
          lds + 32768 + (p) * 16384 + row_ * 64 + ch_ * 8);                  \
    }

#define LDA_Q(p, q)                                                          \
  _Pragma("unroll")                                                          \
  for (int i_ = 0; i_ < 2; ++i_)                                             \
    _Pragma("unroll")                                                        \
    for (int kk_ = 0; kk_ < 2; ++kk_) {                                      \
      int row_ = wr * 128 + ((q) * 2 + i_) * 16 + lr;                        \
      int ch_ = (kk_ * 4 + lk) ^ (lr & 7);                                   \
      af[i_][kk_] = *reinterpret_cast<const bf16x8*>(                        \
          lds + (p) * 16384 + row_ * 64 + ch_ * 8);                          \
    }

// kk_ outermost: 8 independent MFMAs between dependent accumulator reuses
#define MFMA_Q(q)                                                            \
  __builtin_amdgcn_s_setprio(1);                                             \
  _Pragma("unroll")                                                          \
  for (int kk_ = 0; kk_ < 2; ++kk_)                                          \
    _Pragma("unroll")                                                        \
    for (int i_ = 0; i_ < 2; ++i_)                                           \
      _Pragma("unroll")                                                      \
      for (int n_ = 0; n_ < 4; ++n_)                                         \
        acc[(q) * 2 + i_][n_] = __builtin_amdgcn_mfma_f32_16x16x32_bf16(     \
            af[i_][kk_], bq[n_][kk_], acc[(q) * 2 + i_][n_], 0, 0, 0);       \
  __builtin_amdgcn_s_setprio(0);

  STAGE_HALF(A, abase, 0, 0, 0);
  STAGE_HALF(A, abase, 0, 1, 0);
  STAGE_HALF(Bt, bbase, 0, 0, 32768);
  STAGE_HALF(Bt, bbase, 0, 1, 32768);
  STAGE_HALF(Bt, bbase, 1, 0, 49152);
  STAGE_HALF(Bt, bbase, 1, 1, 49152);
  VMCNT(4);
  BAR();

  const int niter = nt >> 1;
  for (int tp = 0; tp < niter; ++tp) {
    const int T = tp << 1;
    const bool more = (T + 2 < nt);
    bf16x8 af[2][2], bq[4][2];

    // ---- tile T (parity 0) ----
    LDB_ALL(0); LDA_Q(0, 0);
    STAGE_HALF(A, abase, T + 1, 0, 16384);
    BAR(); LGKM0(); MFMA_Q(0); BAR();
    LDA_Q(0, 1);
    STAGE_HALF(A, abase, T + 1, 1, 16384);
    BAR(); LGKM0(); MFMA_Q(1); BAR();
    LDA_Q(0, 2);
    if (more) STAGE_HALF(Bt, bbase, T + 2, 0, 32768);
    BAR(); LGKM0(); MFMA_Q(2); BAR();
    LDA_Q(0, 3);
    if (more) { STAGE_HALF(Bt, bbase, T + 2, 1, 32768); VMCNT(4); }
    else VMCNT(0);
    BAR(); LGKM0(); MFMA_Q(3); BAR();

    // ---- tile T+1 (parity 1) ----
    LDB_ALL(1); LDA_Q(1, 0);
    if (more) STAGE_HALF(A, abase, T + 2, 0, 0);
    BAR(); LGKM0(); MFMA_Q(0); BAR();
    LDA_Q(1, 1);
    if (more) STAGE_HALF(A, abase, T + 2, 1, 0);
    BAR(); LGKM0(); MFMA_Q(1); BAR();
    LDA_Q(1, 2);
    if (more) STAGE_HALF(Bt, bbase, T + 3, 0, 49152);
    BAR(); LGKM0(); MFMA_Q(2); BAR();
    LDA_Q(1, 3);
    if (more) { STAGE_HALF(Bt, bbase, T + 3, 1, 49152); VMCNT(4); }
    BAR(); LGKM0(); MFMA_Q(3); BAR();
  }

  const long mrow = m0 + wr * 128;
  const long ncol = n0 + wc * 64;

  if (OUT_BF16) {
#pragma unroll
    for (int n = 0; n < 4; ++n) {
      long col = ncol + n * 16 + lr;
      float bb = bias[col];
#pragma unroll
      for (int m = 0; m < 8; ++m)
#pragma unroll
        for (int j = 0; j < 4; ++j) {
          long row = mrow + m * 16 + lk * 4 + j;
          unsigned h = f2bf(acc[m][n][j] + bb);
          unsigned ph = h | (((unsigned)__shfl_xor((int)h, 1, 64)) << 16);
          unsigned p2 = (unsigned)__shfl_xor((int)ph, 2, 64);
          if ((lane & 3) == 0) {
            uint2 o; o.x = ph; o.y = p2;
            *reinterpret_cast<uint2*>((u16*)Cv + row * N + col) = o;
          }
        }
    }
  } else {
    // f32 epilogue: per-wave LDS transpose (stride 68, 2-way = free) ->
    // fully coalesced f32x4 stores: per instruction, 16-lane groups each
    // write 256B contiguous (4 consecutive rows x 2 full 128B lines).
    __syncthreads();                         // LDS tiles no longer needed
    float* ep = reinterpret_cast<float*>(lds) + wid * (16 * 68);
    float bb[4];
#pragma unroll
    for (int n = 0; n < 4; ++n) bb[n] = bias[ncol + n * 16 + lr];
    const int rr = lane >> 4, cc = lane & 15;
#pragma unroll
    for (int m = 0; m < 8; ++m) {
#pragma unroll
      for (int n = 0; n < 4; ++n)
#pragma unroll
        for (int j = 0; j < 4; ++j)
          ep[(lk * 4 + j) * 68 + n * 16 + lr] = acc[m][n][j] + bb[n];
      asm volatile("s_waitcnt lgkmcnt(0)" ::: "memory");
#pragma unroll
      for (int s = 0; s < 4; ++s) {
        f32x4 v = *reinterpret_cast<const f32x4*>(ep + (s * 4 + rr) * 68 + cc * 4);
        *reinterpret_cast<f32x4*>((float*)Cv + (mrow + m * 16 + s * 4 + rr) * N +
                                  ncol + cc * 4) = v;
      }
      asm volatile("s_waitcnt lgkmcnt(0)" ::: "memory");
    }
  }
#undef STAGE_HALF
#undef LDB_ALL
#undef LDA_Q
#undef MFMA_Q
}

// ---------------- fused attention: 16 q-rows per block, in-place on Q ------
// Q [16*4096][1024] bf16 (overwritten), KV [16][80][2048] bf16 (K = cols
// 0..1023; rows 77..79 masked), Vt [16][1024][96] bf16 (k-pad zeroed).
__global__ __launch_bounds__(256) void attn_fused(u16* __restrict__ Q,
                                                  const u16* __restrict__ KV,
                                                  const u16* __restrict__ Vt) {
  const int blk = blockIdx.x;
  const int b = blk >> 8;               // 256 blocks per batch (4096/16)
  const int q0 = (blk & 255) << 4;
  const long qoff = ((long)b * 4096 + q0) * 1024;
  const int tid = threadIdx.x;
  const int lane = tid & 63, wave = tid >> 6;
  const int lr = lane & 15, lk = lane >> 4;

  __shared__ float S4[4][16][80];
  __shared__ __align__(16) u16 P_lds[16][104];  // bf16 P, stride 104 breaks banks

  // Phase 1: scores via MFMA; wave w covers k-dim slice w*256 .. +255
  f32x4 acc[5] = {};
  const u16* qb = Q + qoff;
  const u16* kb = KV + (long)b * 80 * 2048;
#pragma unroll
  for (int t = 0; t < 8; ++t) {
    int kk = wave * 8 + t;
    bf16x8 qa = *reinterpret_cast<const bf16x8*>(qb + lr * 1024 + kk * 32 + lk * 8);
#pragma unroll
    for (int n = 0; n < 5; ++n) {
      bf16x8 kf = *reinterpret_cast<const bf16x8*>(kb + (long)(n * 16 + lr) * 2048 + kk * 32 + lk * 8);
      acc[n] = __builtin_amdgcn_mfma_f32_16x16x32_bf16(qa, kf, acc[n], 0, 0, 0);
    }
  }
#pragma unroll
  for (int n = 0; n < 5; ++n)
#pragma unroll
    for (int j = 0; j < 4; ++j)
      S4[wave][lk * 4 + j][n * 16 + lr] = acc[n][j];
  __syncthreads();

  // Phase 2: cross-wave reduce + softmax -> P_lds (bf16, cols 80..95 zeroed)
  {
    const int r = tid >> 4, ci = tid & 15;
    const float scale = 0.088388347648318447f;  // 1/sqrt(128)
    float v[5];
    float mx = -3e38f;
#pragma unroll
    for (int i = 0; i < 5; ++i) {
      int c = ci + 16 * i;
      float s = (S4[0][r][c] + S4[1][r][c]) + (S4[2][r][c] + S4[3][r][c]);
      s *= scale;
      if (c >= 77) s = -3e38f;
      v[i] = s;
      mx = fmaxf(mx, s);
    }
#pragma unroll
    for (int off = 1; off < 16; off <<= 1) mx = fmaxf(mx, __shfl_xor(mx, off, 64));
    float sum = 0.f, e[5];
#pragma unroll
    for (int i = 0; i < 5; ++i) { e[i] = __expf(v[i] - mx); sum += e[i]; }
#pragma unroll
    for (int off = 1; off < 16; off <<= 1) sum += __shfl_xor(sum, off, 64);
    float inv = 1.f / sum;
#pragma unroll
    for (int i = 0; i < 5; ++i) P_lds[r][ci + 16 * i] = f2bf(e[i] * inv);
    P_lds[r][80 + ci] = 0;
  }
  __syncthreads();

  // Phase 3: PV via MFMA. A = P (rows = q), B = Vt rows (cols = e), K = 96.
  bf16x8 pa[3];
#pragma unroll
  for (int kk = 0; kk < 3; ++kk)
    pa[kk] = *reinterpret_cast<const bf16x8*>(&P_lds[lr][kk * 32 + lk * 8]);
  const u16* vt = Vt + (long)b * 1024 * 96;
  u16* ob = Q + qoff;
#pragma unroll
  for (int n = 0; n < 16; ++n) {
    int col = wave * 256 + n * 16 + lr;
    f32x4 o = {};
#pragma unroll
    for (int kk = 0; kk < 3; ++kk) {
      bf16x8 vq = *reinterpret_cast<const bf16x8*>(vt + (long)col * 96 + kk * 32 + lk * 8);
      o = __builtin_amdgcn_mfma_f32_16x16x32_bf16(pa[kk], vq, o, 0, 0, 0);
    }
#pragma unroll
    for (int j = 0; j < 4; ++j) {
      unsigned h = f2bf(o[j]);
      unsigned ph = h | (((unsigned)__shfl_xor((int)h, 1, 64)) << 16);
      unsigned p2 = (unsigned)__shfl_xor((int)ph, 2, 64);
      if ((lane & 3) == 0) {
        uint2 st; st.x = ph; st.y = p2;
        *reinterpret_cast<uint2*>(ob + (long)(lk * 4 + j) * 1024 + col) = st;
      }
    }
  }
}

extern "C" void kernel_launch(void* const* d_in, const int* in_sizes, int n_in,
                              void* d_out, int out_size, void* d_ws, size_t ws_size,
                              hipStream_t stream) {
  const float* x  = (const float*)d_in[0];
  const float* y  = (const float*)d_in[1];
  const float* Wq = (const float*)d_in[2];
  const float* bq = (const float*)d_in[3];
  const float* Wk = (const float*)d_in[4];
  const float* bk = (const float*)d_in[5];
  const float* Wv = (const float*)d_in[6];
  const float* bv = (const float*)d_in[7];
  const float* Wo = (const float*)d_in[8];
  const float* bo = (const float*)d_in[9];

  const int B = 16, Lq = 4096, D = 1024, Dc = 768, Lp = 80;
  const long Mq = (long)B * Lq;  // 65536

  char* p = (char*)d_ws;
  u16* Qb   = (u16*)p; p += (size_t)Mq * D * 2;       // Q, then attn out (in-place)
  u16* Wqt  = (u16*)p; p += (size_t)D * D * 2;
  u16* Wkvt = (u16*)p; p += (size_t)2 * D * Dc * 2;   // [2048][768]: Wk^T | Wv^T
  u16* Wot  = (u16*)p; p += (size_t)D * D * 2;
  u16* yp   = (u16*)p; p += (size_t)B * Lp * Dc * 2;  // [16][80][768], pad zeroed
  u16* KV   = (u16*)p; p += (size_t)B * Lp * 2 * D * 2; // [16][80][2048]
  u16* Vt   = (u16*)p; p += (size_t)B * D * 96 * 2;   // [16][1024][96]
  float* bkv = (float*)p; p += (size_t)2 * D * 4;     // [2048]
  u16* xb   = (u16*)d_out;  // scratch: x as bf16 lives in d_out until final GEMM

  (void)hipFuncSetAttribute(reinterpret_cast<const void*>(&gemm8<true>),
                            hipFuncAttributeMaxDynamicSharedMemorySize, 131072);
  (void)hipFuncSetAttribute(reinterpret_cast<const void*>(&gemm8<false>),
                            hipFuncAttributeMaxDynamicSharedMemorySize, 131072);

  // conversions
  cvt_f32_bf16<<<(int)(Mq * D / 1024), 256, 0, stream>>>(x, xb, Mq * D / 4);
  transpose_cvt<<<dim3(D / 32, D / 32), 256, 0, stream>>>(Wq, Wqt, D, D);
  transpose_cvt<<<dim3(D / 32, Dc / 32), 256, 0, stream>>>(Wk, Wkvt, Dc, D);
  transpose_cvt<<<dim3(D / 32, Dc / 32), 256, 0, stream>>>(Wv, Wkvt + (size_t)D * Dc, Dc, D);
  transpose_cvt<<<dim3(D / 32, D / 32), 256, 0, stream>>>(Wo, Wot, D, D);
  cvt_y_pad<<<(B * Lp * Dc / 4) / 256, 256, 0, stream>>>(y, yp);
  concat_bias<<<8, 256, 0, stream>>>(bk, bv, bkv);

  // fused K|V projection: [1280][768] @ [768][2048] -> [1280][2048]
  gemm8<true><<<(1280 / 256) * (2 * D / 256), 512, 131072, stream>>>(
      yp, Wkvt, bkv, KV, B * Lp, 2 * D, Dc);

  // V transpose for MFMA PV: KV cols 1024.. -> [16][1024][96]
  transpose_v<<<dim3(D / 32, 3, B), 256, 0, stream>>>(KV, Vt);

  // Q projection: [65536][1024] @ [1024][1024] -> [65536][1024] bf16
  gemm8<true><<<(int)(Mq / 256) * (D / 256), 512, 131072, stream>>>(xb, Wqt, bq, Qb, (int)Mq, D, D);

  // fused attention, writes back into Qb
  attn_fused<<<(int)(Mq / 16), 256, 0, stream>>>(Qb, KV, Vt);

  // output projection: [65536][1024] @ [1024][1024] -> d_out f32
  gemm8<false><<<(int)(Mq / 256) * (D / 256), 512, 131072, stream>>>(Qb, Wot, bo, d_out, (int)Mq, D, D);
}